// Round 10
// baseline (474.425 us; speedup 1.0000x reference)
//
#include <hip/hip_runtime.h>
#include <hip/hip_cooperative_groups.h>

namespace cg = cooperative_groups;

typedef __attribute__((ext_vector_type(4))) int i32x4;

#define N_NODES   4000000
#define N_EDGES   12000000
#define N_GRAPHS  1000000

// ---- micro-bin params ----
#define NMB       3907       // micro-bins of 256 dst-graphs (ceil(1e6/256))
#define MBCAP     4096       // recs per micro-bin (mean 3072, +18 sigma)
#define LCAP      9          // LDS staging recs per micro-bin
#define SBLOCKS   256
#define SEPB      46880      // 256*46880 >= 12M, multiple of 4
#define NQUAD     977        // reduce blocks; 4 micro-bins each (3908 >= 3907)
// per reduce block: 1024 graphs, 4096 nodes, 32 KB dyn LDS

// rec layout (u32): [31:24]=graph&255, [23:2]=src (N_NODES<2^22), [1:0]=dst&3

// ================= fold =================

__global__ __launch_bounds__(256) void fold_kernel(
    const float* __restrict__ Wgcn, const float* __restrict__ bgcn,
    const float* __restrict__ W1, const float* __restrict__ b1,
    float* __restrict__ fold) {
  int t = threadIdx.x;
  if (t < 128) {
    int j = t >> 2, c = t & 3;
    float s = 0.f;
    for (int k = 0; k < 32; ++k) s += Wgcn[c * 32 + k] * W1[(4 + k) * 32 + j];
    fold[j * 4 + c] = s;                    // Wg1T[j][c]
  }
  if (t < 32) {
    float s = 0.f;
    for (int k = 0; k < 32; ++k) s += bgcn[k] * W1[(4 + k) * 32 + t];
    fold[128 + t] = b1[t] + 4.0f * s;       // b1p[j]
  }
}

// ================= binscatter (u32 recs) =================

__global__ __launch_bounds__(512) void binscatter_kernel(
    const int* __restrict__ src, const int* __restrict__ dst,
    unsigned* __restrict__ gcur, unsigned* __restrict__ recs) {
  extern __shared__ char smem[];
  unsigned* buf = (unsigned*)smem;                     // [NMB*LCAP]
  unsigned* cnt = (unsigned*)(smem + NMB * LCAP * 4);  // [NMB]
  int t = threadIdx.x;
  for (int i = t; i < NMB; i += 512) cnt[i] = 0;
  __syncthreads();
  const int base = blockIdx.x * SEPB;
  const int limit = min(SEPB, N_EDGES - base);   // >0, multiple of 4
  const int V = limit >> 2;
  const i32x4* src4 = (const i32x4*)(src + base);
  const i32x4* dst4 = (const i32x4*)(dst + base);
  const int nrounds = (V + 1023) / 1024;

  i32x4 cs0 = {0,0,0,0}, cd0 = {0,0,0,0}, cs1 = {0,0,0,0}, cd1 = {0,0,0,0};
  {
    int i0 = t, i1 = t + 512;
    if (i0 < V) { cs0 = __builtin_nontemporal_load(src4 + i0);
                  cd0 = __builtin_nontemporal_load(dst4 + i0); }
    if (i1 < V) { cs1 = __builtin_nontemporal_load(src4 + i1);
                  cd1 = __builtin_nontemporal_load(dst4 + i1); }
  }
  for (int r = 0; r < nrounds; ++r) {
    i32x4 ns0 = {0,0,0,0}, nd0 = {0,0,0,0}, ns1 = {0,0,0,0}, nd1 = {0,0,0,0};
    if (r + 1 < nrounds) {
      int j0 = (r + 1) * 1024 + t, j1 = j0 + 512;
      if (j0 < V) { ns0 = __builtin_nontemporal_load(src4 + j0);
                    nd0 = __builtin_nontemporal_load(dst4 + j0); }
      if (j1 < V) { ns1 = __builtin_nontemporal_load(src4 + j1);
                    nd1 = __builtin_nontemporal_load(dst4 + j1); }
    }
    int idx0 = r * 1024 + t;
#pragma unroll
    for (int half = 0; half < 2; ++half) {
      int idx = idx0 + half * 512;
      if (idx < V) {
        i32x4 vs = half ? cs1 : cs0;
        i32x4 vd = half ? cd1 : cd0;
#pragma unroll
        for (int k = 0; k < 4; ++k) {
          unsigned s = (unsigned)vs[k];
          unsigned d = (unsigned)vd[k];
          unsigned graph = d >> 2;
          unsigned bin   = graph >> 8;
          unsigned rec = ((graph & 255u) << 24) | (s << 2) | (d & 3u);
          unsigned pos = atomicAdd(&cnt[bin], 1u);
          if (pos < LCAP) buf[bin * LCAP + pos] = rec;
          else {  // rare spill
            unsigned p = atomicAdd(&gcur[bin], 1u);
            if (p < MBCAP) recs[(size_t)bin * MBCAP + p] = rec;
          }
        }
      }
    }
    __syncthreads();
    bool fin = (r == nrounds - 1);
    for (int bin = t; bin < NMB; bin += 512) {
      unsigned c = cnt[bin]; if (c > LCAP) c = LCAP;
      unsigned nn = fin ? c : (c & ~7u);   // 32B bursts
      if (nn) {
        unsigned pos = atomicAdd(&gcur[bin], nn);
        if (pos + nn <= MBCAP) {
          unsigned* dp = recs + (size_t)bin * MBCAP + pos;
          for (unsigned i2 = 0; i2 < nn; ++i2) dp[i2] = buf[bin * LCAP + i2];
        }
      }
      unsigned rem2 = c - nn;
      for (unsigned i2 = 0; i2 < rem2; ++i2)
        buf[bin * LCAP + i2] = buf[bin * LCAP + nn + i2];
      cnt[bin] = rem2;
    }
    __syncthreads();
    cs0 = ns0; cd0 = nd0; cs1 = ns1; cd1 = nd1;
  }
}

// ================= fused cooperative reduce (quad of micro-bins) =================

__global__ __launch_bounds__(512, 8) void fusedreduce_kernel(
    const unsigned* __restrict__ recs, const unsigned* __restrict__ gcur,
    float4* __restrict__ dsi4, const float4* __restrict__ state4,
    const float* __restrict__ W1, const float* __restrict__ fold,
    const float* __restrict__ W2, const float* __restrict__ b2,
    float* __restrict__ out) {
  extern __shared__ float dynsm[];
  unsigned* degL = (unsigned*)dynsm;   // phase1; becomes dinvL in place
  float* dinvL = dynsm;                // [4096]
  float* accL  = dynsm + 4096;         // [4096]
  __shared__ float4 w1aT[32], wg1T[32];
  __shared__ float b1p[32], w2s[32];
  int t = threadIdx.x, qb = blockIdx.x;
  if (t < 32) {
    w1aT[t] = make_float4(W1[t], W1[32 + t], W1[64 + t], W1[96 + t]);
    wg1T[t] = ((const float4*)fold)[t];
    b1p[t]  = fold[128 + t];
    w2s[t]  = W2[t];
  }
  for (int i = t; i < 4096; i += 512) { degL[i] = 0u; accL[i] = 0.f; }
  __syncthreads();
  unsigned n[4];
  const unsigned* rp[4];
#pragma unroll
  for (int s = 0; s < 4; ++s) {
    int mb = qb * 4 + s;
    unsigned c = (mb < NMB) ? gcur[mb] : 0u;
    n[s] = (c > MBCAP) ? (unsigned)MBCAP : c;
    rp[s] = recs + (size_t)mb * MBCAP;
  }
  unsigned mx = max(max(n[0], n[1]), max(n[2], n[3]));
  // ---- phase 1: degree histogram (4 sub-bin streams) ----
  for (unsigned i = t; i < mx; i += 512) {
#pragma unroll
    for (int s = 0; s < 4; ++s) {
      if (i < n[s]) {
        unsigned r = __builtin_nontemporal_load(rp[s] + i);
        unsigned lg = (unsigned)(s * 256) + (r >> 24);
        atomicAdd(&degL[lg * 4 + (r & 3u)], 1u);
      }
    }
  }
  __syncthreads();
  int nb = qb * 4096;
  for (int i = t; i < 4096; i += 512) {
    int node = nb + i;
    float dv = rsqrtf((float)(degL[i] + 1u));  // +1 self loop
    dinvL[i] = dv;                              // in-place over degL
    if (node < N_NODES) {
      float4 s = state4[node];
      dsi4[node] = make_float4(dv * s.x, dv * s.y, dv * s.z, dv * s.w);
    }
  }
  __threadfence();
  cg::this_grid().sync();
  // ---- phase 2: gather + accumulate (ILP-4 via sub-bin streams) ----
  for (unsigned i = t; i < mx; i += 512) {
    unsigned r0 = 0, r1 = 0, r2 = 0, r3 = 0;
    bool v0 = i < n[0], v1 = i < n[1], v2 = i < n[2], v3 = i < n[3];
    if (v0) r0 = __builtin_nontemporal_load(rp[0] + i);
    if (v1) r1 = __builtin_nontemporal_load(rp[1] + i);
    if (v2) r2 = __builtin_nontemporal_load(rp[2] + i);
    if (v3) r3 = __builtin_nontemporal_load(rp[3] + i);
    if (v0) {
      unsigned lg = (r0 >> 24), src = (r0 >> 2) & 0x3FFFFFu;
      float w = dinvL[lg * 4 + (r0 & 3u)];
      float4 m = dsi4[src];
      float* a = accL + lg * 4;
      atomicAdd(a + 0, w * m.x); atomicAdd(a + 1, w * m.y);
      atomicAdd(a + 2, w * m.z); atomicAdd(a + 3, w * m.w);
    }
    if (v1) {
      unsigned lg = 256u + (r1 >> 24), src = (r1 >> 2) & 0x3FFFFFu;
      float w = dinvL[lg * 4 + (r1 & 3u)];
      float4 m = dsi4[src];
      float* a = accL + lg * 4;
      atomicAdd(a + 0, w * m.x); atomicAdd(a + 1, w * m.y);
      atomicAdd(a + 2, w * m.z); atomicAdd(a + 3, w * m.w);
    }
    if (v2) {
      unsigned lg = 512u + (r2 >> 24), src = (r2 >> 2) & 0x3FFFFFu;
      float w = dinvL[lg * 4 + (r2 & 3u)];
      float4 m = dsi4[src];
      float* a = accL + lg * 4;
      atomicAdd(a + 0, w * m.x); atomicAdd(a + 1, w * m.y);
      atomicAdd(a + 2, w * m.z); atomicAdd(a + 3, w * m.w);
    }
    if (v3) {
      unsigned lg = 768u + (r3 >> 24), src = (r3 >> 2) & 0x3FFFFFu;
      float w = dinvL[lg * 4 + (r3 & 3u)];
      float4 m = dsi4[src];
      float* a = accL + lg * 4;
      atomicAdd(a + 0, w * m.x); atomicAdd(a + 1, w * m.y);
      atomicAdd(a + 2, w * m.z); atomicAdd(a + 3, w * m.w);
    }
  }
  __syncthreads();
  // ---- epilogue: self-loops + fused MLP ----
  for (int gi = t; gi < 1024; gi += 512) {
    int g = qb * 1024 + gi;
    if (g >= N_GRAPHS) break;
    float4 s0 = state4[4 * g + 0], s1 = state4[4 * g + 1];
    float4 s2 = state4[4 * g + 2], s3 = state4[4 * g + 3];
    float d0 = dinvL[gi * 4 + 0], d1 = dinvL[gi * 4 + 1];
    float d2 = dinvL[gi * 4 + 2], d3 = dinvL[gi * 4 + 3];
    float q0 = d0 * d0, q1 = d1 * d1, q2 = d2 * d2, q3 = d3 * d3;
    float ax = accL[gi * 4 + 0] + q0 * s0.x + q1 * s1.x + q2 * s2.x + q3 * s3.x;
    float ay = accL[gi * 4 + 1] + q0 * s0.y + q1 * s1.y + q2 * s2.y + q3 * s3.y;
    float az = accL[gi * 4 + 2] + q0 * s0.z + q1 * s1.z + q2 * s2.z + q3 * s3.z;
    float aw = accL[gi * 4 + 3] + q0 * s0.w + q1 * s1.w + q2 * s2.w + q3 * s3.w;
    float vx = s0.x + s1.x + s2.x + s3.x;
    float vy = s0.y + s1.y + s2.y + s3.y;
    float vz = s0.z + s1.z + s2.z + s3.z;
    float vw = s0.w + s1.w + s2.w + s3.w;
    float accum = b2[0];
#pragma unroll 4
    for (int j = 0; j < 32; ++j) {
      float4 wa = w1aT[j], wg = wg1T[j];
      float h = b1p[j]
              + vx * wa.x + vy * wa.y + vz * wa.z + vw * wa.w
              + ax * wg.x + ay * wg.y + az * wg.z + aw * wg.w;
      accum += fmaxf(h, 0.f) * w2s[j];
    }
    out[g] = accum;
  }
}

// ================= split fallback (same structure, no grid sync) =================

__global__ __launch_bounds__(512) void bindeg_kernel(
    const unsigned* __restrict__ recs, const unsigned* __restrict__ gcur,
    const float4* __restrict__ state4,
    float* __restrict__ dinv, float4* __restrict__ dsi4) {
  __shared__ unsigned degL[4096];
  int t = threadIdx.x, qb = blockIdx.x;
  for (int i = t; i < 4096; i += 512) degL[i] = 0;
  __syncthreads();
  for (int s = 0; s < 4; ++s) {
    int mb = qb * 4 + s;
    unsigned c = (mb < NMB) ? gcur[mb] : 0u;
    unsigned nn = (c > MBCAP) ? (unsigned)MBCAP : c;
    const unsigned* rp = recs + (size_t)mb * MBCAP;
    for (unsigned i = t; i < nn; i += 512) {
      unsigned r = __builtin_nontemporal_load(rp + i);
      unsigned lg = (unsigned)(s * 256) + (r >> 24);
      atomicAdd(&degL[lg * 4 + (r & 3u)], 1u);
    }
  }
  __syncthreads();
  int nb = qb * 4096;
  for (int i = t; i < 4096; i += 512) {
    int node = nb + i;
    if (node < N_NODES) {
      float dv = rsqrtf((float)(degL[i] + 1u));
      dinv[node] = dv;
      float4 s = state4[node];
      dsi4[node] = make_float4(dv * s.x, dv * s.y, dv * s.z, dv * s.w);
    }
  }
}

__global__ __launch_bounds__(512, 8) void binreduce_kernel(
    const unsigned* __restrict__ recs, const unsigned* __restrict__ gcur,
    const float* __restrict__ dinv, const float4* __restrict__ dsi4,
    const float4* __restrict__ state4,
    const float* __restrict__ W1, const float* __restrict__ fold,
    const float* __restrict__ W2, const float* __restrict__ b2,
    float* __restrict__ out) {
  extern __shared__ float dynsm[];
  float* dinvL = dynsm;
  float* accL  = dynsm + 4096;
  __shared__ float4 w1aT[32], wg1T[32];
  __shared__ float b1p[32], w2s[32];
  int t = threadIdx.x, qb = blockIdx.x;
  if (t < 32) {
    w1aT[t] = make_float4(W1[t], W1[32 + t], W1[64 + t], W1[96 + t]);
    wg1T[t] = ((const float4*)fold)[t];
    b1p[t]  = fold[128 + t];
    w2s[t]  = W2[t];
  }
  int nb = qb * 4096;
  for (int i = t; i < 4096; i += 512) {
    int node = nb + i;
    dinvL[i] = (node < N_NODES) ? dinv[node] : 0.f;
    accL[i]  = 0.f;
  }
  __syncthreads();
  unsigned n[4];
  const unsigned* rp[4];
#pragma unroll
  for (int s = 0; s < 4; ++s) {
    int mb = qb * 4 + s;
    unsigned c = (mb < NMB) ? gcur[mb] : 0u;
    n[s] = (c > MBCAP) ? (unsigned)MBCAP : c;
    rp[s] = recs + (size_t)mb * MBCAP;
  }
  unsigned mx = max(max(n[0], n[1]), max(n[2], n[3]));
  for (unsigned i = t; i < mx; i += 512) {
    unsigned r0 = 0, r1 = 0, r2 = 0, r3 = 0;
    bool v0 = i < n[0], v1 = i < n[1], v2 = i < n[2], v3 = i < n[3];
    if (v0) r0 = __builtin_nontemporal_load(rp[0] + i);
    if (v1) r1 = __builtin_nontemporal_load(rp[1] + i);
    if (v2) r2 = __builtin_nontemporal_load(rp[2] + i);
    if (v3) r3 = __builtin_nontemporal_load(rp[3] + i);
    if (v0) {
      unsigned lg = (r0 >> 24), src = (r0 >> 2) & 0x3FFFFFu;
      float w = dinvL[lg * 4 + (r0 & 3u)];
      float4 m = dsi4[src];
      float* a = accL + lg * 4;
      atomicAdd(a + 0, w * m.x); atomicAdd(a + 1, w * m.y);
      atomicAdd(a + 2, w * m.z); atomicAdd(a + 3, w * m.w);
    }
    if (v1) {
      unsigned lg = 256u + (r1 >> 24), src = (r1 >> 2) & 0x3FFFFFu;
      float w = dinvL[lg * 4 + (r1 & 3u)];
      float4 m = dsi4[src];
      float* a = accL + lg * 4;
      atomicAdd(a + 0, w * m.x); atomicAdd(a + 1, w * m.y);
      atomicAdd(a + 2, w * m.z); atomicAdd(a + 3, w * m.w);
    }
    if (v2) {
      unsigned lg = 512u + (r2 >> 24), src = (r2 >> 2) & 0x3FFFFFu;
      float w = dinvL[lg * 4 + (r2 & 3u)];
      float4 m = dsi4[src];
      float* a = accL + lg * 4;
      atomicAdd(a + 0, w * m.x); atomicAdd(a + 1, w * m.y);
      atomicAdd(a + 2, w * m.z); atomicAdd(a + 3, w * m.w);
    }
    if (v3) {
      unsigned lg = 768u + (r3 >> 24), src = (r3 >> 2) & 0x3FFFFFu;
      float w = dinvL[lg * 4 + (r3 & 3u)];
      float4 m = dsi4[src];
      float* a = accL + lg * 4;
      atomicAdd(a + 0, w * m.x); atomicAdd(a + 1, w * m.y);
      atomicAdd(a + 2, w * m.z); atomicAdd(a + 3, w * m.w);
    }
  }
  __syncthreads();
  for (int gi = t; gi < 1024; gi += 512) {
    int g = qb * 1024 + gi;
    if (g >= N_GRAPHS) break;
    float4 s0 = state4[4 * g + 0], s1 = state4[4 * g + 1];
    float4 s2 = state4[4 * g + 2], s3 = state4[4 * g + 3];
    float d0 = dinvL[gi * 4 + 0], d1 = dinvL[gi * 4 + 1];
    float d2 = dinvL[gi * 4 + 2], d3 = dinvL[gi * 4 + 3];
    float q0 = d0 * d0, q1 = d1 * d1, q2 = d2 * d2, q3 = d3 * d3;
    float ax = accL[gi * 4 + 0] + q0 * s0.x + q1 * s1.x + q2 * s2.x + q3 * s3.x;
    float ay = accL[gi * 4 + 1] + q0 * s0.y + q1 * s1.y + q2 * s2.y + q3 * s3.y;
    float az = accL[gi * 4 + 2] + q0 * s0.z + q1 * s1.z + q2 * s2.z + q3 * s3.z;
    float aw = accL[gi * 4 + 3] + q0 * s0.w + q1 * s1.w + q2 * s2.w + q3 * s3.w;
    float vx = s0.x + s1.x + s2.x + s3.x;
    float vy = s0.y + s1.y + s2.y + s3.y;
    float vz = s0.z + s1.z + s2.z + s3.z;
    float vw = s0.w + s1.w + s2.w + s3.w;
    float accum = b2[0];
#pragma unroll 4
    for (int j = 0; j < 32; ++j) {
      float4 wa = w1aT[j], wg = wg1T[j];
      float h = b1p[j]
              + vx * wa.x + vy * wa.y + vz * wa.z + vw * wa.w
              + ax * wg.x + ay * wg.y + az * wg.z + aw * wg.w;
      accum += fmaxf(h, 0.f) * w2s[j];
    }
    out[g] = accum;
  }
}

// ================= round-3 emergency fallback =================

__global__ __launch_bounds__(256) void deg_kernel(
    const i32x4* __restrict__ dst4, unsigned* __restrict__ deg) {
  int stride = gridDim.x * blockDim.x;
  for (int e = blockIdx.x * blockDim.x + threadIdx.x; e < N_EDGES / 4; e += stride) {
    i32x4 d = __builtin_nontemporal_load(dst4 + e);
    atomicAdd(&deg[d.x], 1u); atomicAdd(&deg[d.y], 1u);
    atomicAdd(&deg[d.z], 1u); atomicAdd(&deg[d.w], 1u);
  }
}

__global__ __launch_bounds__(256) void dinv_kernel(unsigned* __restrict__ degdinv) {
  int i = blockIdx.x * blockDim.x + threadIdx.x;
  if (i < N_NODES) {
    float dv = rsqrtf((float)(degdinv[i] + 1u));
    reinterpret_cast<float*>(degdinv)[i] = dv;
  }
}

__global__ __launch_bounds__(256) void scatter_kernel(
    const i32x4* __restrict__ src4, const i32x4* __restrict__ dst4,
    const float* __restrict__ dinv, const float4* __restrict__ state4,
    float* __restrict__ acc) {
  int stride = gridDim.x * blockDim.x;
  for (int e = blockIdx.x * blockDim.x + threadIdx.x; e < N_EDGES / 4; e += stride) {
    i32x4 s4 = __builtin_nontemporal_load(src4 + e);
    i32x4 d4 = __builtin_nontemporal_load(dst4 + e);
#pragma unroll
    for (int u = 0; u < 4; ++u) {
      int s = (u == 0) ? s4.x : (u == 1) ? s4.y : (u == 2) ? s4.z : s4.w;
      int d = (u == 0) ? d4.x : (u == 1) ? d4.y : (u == 2) ? d4.z : d4.w;
      float w = dinv[s] * dinv[d];
      float4 st = state4[s];
      float* base = acc + (size_t)(d >> 2) * 4;
      atomicAdd(base + 0, w * st.x); atomicAdd(base + 1, w * st.y);
      atomicAdd(base + 2, w * st.z); atomicAdd(base + 3, w * st.w);
    }
  }
}

__global__ __launch_bounds__(256) void final_kernel(
    const float4* __restrict__ state4, const float4* __restrict__ dinv4,
    const float4* __restrict__ acc4, const float* __restrict__ W1,
    const float* __restrict__ fold, const float* __restrict__ W2,
    const float* __restrict__ b2, float* __restrict__ out) {
  __shared__ float4 w1aT[32], wg1T[32];
  __shared__ float b1p[32], w2s[32];
  int t = threadIdx.x;
  if (t < 32) {
    w1aT[t] = make_float4(W1[t], W1[32 + t], W1[64 + t], W1[96 + t]);
    wg1T[t] = ((const float4*)fold)[t];
    b1p[t]  = fold[128 + t];
    w2s[t]  = W2[t];
  }
  __syncthreads();
  int b = blockIdx.x * blockDim.x + t;
  if (b >= N_GRAPHS) return;
  float4 s0 = state4[4 * b + 0], s1 = state4[4 * b + 1];
  float4 s2 = state4[4 * b + 2], s3 = state4[4 * b + 3];
  float4 dv = dinv4[b];
  float4 a  = acc4[b];
  float q0 = dv.x * dv.x, q1 = dv.y * dv.y, q2 = dv.z * dv.z, q3 = dv.w * dv.w;
  a.x += q0 * s0.x + q1 * s1.x + q2 * s2.x + q3 * s3.x;
  a.y += q0 * s0.y + q1 * s1.y + q2 * s2.y + q3 * s3.y;
  a.z += q0 * s0.z + q1 * s1.z + q2 * s2.z + q3 * s3.z;
  a.w += q0 * s0.w + q1 * s1.w + q2 * s2.w + q3 * s3.w;
  float4 vs;
  vs.x = s0.x + s1.x + s2.x + s3.x;
  vs.y = s0.y + s1.y + s2.y + s3.y;
  vs.z = s0.z + s1.z + s2.z + s3.z;
  vs.w = s0.w + s1.w + s2.w + s3.w;
  float accum = b2[0];
#pragma unroll
  for (int j = 0; j < 32; ++j) {
    float4 wa = w1aT[j], wg = wg1T[j];
    float h = b1p[j]
            + vs.x * wa.x + vs.y * wa.y + vs.z * wa.z + vs.w * wa.w
            + a.x * wg.x + a.y * wg.y + a.z * wg.z + a.w * wg.w;
    accum += fmaxf(h, 0.f) * w2s[j];
  }
  out[b] = accum;
}

// ================= launch =================

extern "C" void kernel_launch(void* const* d_in, const int* in_sizes, int n_in,
                              void* d_out, int out_size, void* d_ws, size_t ws_size,
                              hipStream_t stream) {
  const float* state = (const float*)d_in[0];
  const int*   ei    = (const int*)d_in[1];   // int32: [2][N_EDGES]
  const float* Wgcn  = (const float*)d_in[2];
  const float* bgcn  = (const float*)d_in[3];
  const float* W1    = (const float*)d_in[4];
  const float* b1    = (const float*)d_in[5];
  const float* W2    = (const float*)d_in[6];
  const float* b2    = (const float*)d_in[7];
  float* out = (float*)d_out;

  char* ws = (char*)d_ws;
  const size_t MB = 1024u * 1024u;

  const size_t recs_bytes = (size_t)NMB * MBCAP * 4;               // 64,012,288
  const size_t dinv_off   = recs_bytes;                             // 16 MB
  const size_t dsi_off    = dinv_off + (size_t)N_NODES * 4;         // 16B-aligned
  const size_t gcur_off   = (dsi_off + (size_t)N_NODES * 16 + 255) & ~(size_t)255;
  const size_t need_bin   = gcur_off + 16384 + 1024;                // ~144 MB

  const size_t scat_smem = (size_t)NMB * LCAP * 4 + NMB * 4;        // 156,280 B
  const size_t red_smem  = 2 * 4096 * 4;                            // 32 KiB

  if (ws_size >= need_bin) {
    unsigned*       recs = (unsigned*)ws;
    float*          dinv = (float*)(ws + dinv_off);
    float4*         dsi4 = (float4*)(ws + dsi_off);
    unsigned*       gcur = (unsigned*)(ws + gcur_off);
    float*          fold = (float*)(ws + gcur_off + 16384);
    const float4*   state4 = (const float4*)state;

    (void)hipFuncSetAttribute((const void*)binscatter_kernel,
        hipFuncAttributeMaxDynamicSharedMemorySize, 160 * 1024);

    (void)hipMemsetAsync(gcur, 0, 16384, stream);
    fold_kernel<<<1, 128, 0, stream>>>(Wgcn, bgcn, W1, b1, fold);
    binscatter_kernel<<<SBLOCKS, 512, scat_smem, stream>>>(
        ei, ei + N_EDGES, gcur, recs);

    // try cooperative fused path
    bool coop_ok = false;
    {
      int dev = 0;
      (void)hipGetDevice(&dev);
      int coop_attr = 0;
      (void)hipDeviceGetAttribute(&coop_attr, hipDeviceAttributeCooperativeLaunch, dev);
      int numCU = 0;
      (void)hipDeviceGetAttribute(&numCU, hipDeviceAttributeMultiprocessorCount, dev);
      int maxblk = 0;
      hipError_t oe = hipOccupancyMaxActiveBlocksPerMultiprocessor(
          &maxblk, fusedreduce_kernel, 512, red_smem);
      if (coop_attr && oe == hipSuccess && (long)maxblk * numCU >= NQUAD) {
        const unsigned* recsc = recs;
        const unsigned* gcurc = gcur;
        const float* W1p = W1; const float* foldp = fold;
        const float* W2p = W2; const float* b2p = b2;
        void* args[] = {(void*)&recsc, (void*)&gcurc, (void*)&dsi4, (void*)&state4,
                        (void*)&W1p, (void*)&foldp, (void*)&W2p, (void*)&b2p,
                        (void*)&out};
        hipError_t le = hipLaunchCooperativeKernel(
            fusedreduce_kernel, dim3(NQUAD), dim3(512), args,
            (unsigned)red_smem, stream);
        coop_ok = (le == hipSuccess);
      }
    }
    if (!coop_ok) {
      bindeg_kernel<<<NQUAD, 512, 0, stream>>>(recs, gcur, state4, dinv, dsi4);
      binreduce_kernel<<<NQUAD, 512, red_smem, stream>>>(
          recs, gcur, dinv, dsi4, state4, W1, fold, W2, b2, out);
    }
    return;
  }

  // emergency fallback (33 MB): round-3 atomic-scatter path
  {
    unsigned* deg  = (unsigned*)ws;
    float*    acc  = (float*)(ws + 16 * MB);
    float*    fold = (float*)(ws + 32 * MB);
    (void)hipMemsetAsync(d_ws, 0, 32 * MB + 1024, stream);
    fold_kernel<<<1, 128, 0, stream>>>(Wgcn, bgcn, W1, b1, fold);
    deg_kernel<<<4096, 256, 0, stream>>>((const i32x4*)(ei + N_EDGES), deg);
    dinv_kernel<<<(N_NODES + 255) / 256, 256, 0, stream>>>(deg);
    scatter_kernel<<<8192, 256, 0, stream>>>(
        (const i32x4*)ei, (const i32x4*)(ei + N_EDGES),
        (const float*)deg, (const float4*)state, acc);
    final_kernel<<<(N_GRAPHS + 255) / 256, 256, 0, stream>>>(
        (const float4*)state, (const float4*)deg, (const float4*)acc,
        W1, fold, W2, b2, out);
  }
}

// Round 11
// 429.117 us; speedup vs baseline: 1.1056x; 1.1056x over previous
//
#include <hip/hip_runtime.h>
#include <hip/hip_cooperative_groups.h>

namespace cg = cooperative_groups;

typedef unsigned long long u64;
typedef __attribute__((ext_vector_type(4))) int i32x4;
typedef __attribute__((ext_vector_type(2))) unsigned long long u64x2;

#define N_NODES   4000000
#define N_EDGES   12000000
#define N_GRAPHS  1000000

// ---- bin-path params ----
#define NBIN      977        // bins of 1024 dst-graphs
#define GPBIN     1024
#define NPBIN     4096       // nodes per bin
#define BINCAP    14336      // recs/bin capacity (mean 12288, +18 sigma)
#define LCAP      16         // LDS staging recs per bin
#define SBLOCKS   256
#define SEPB      46880      // 256*46880 >= 12M, multiple of 32

// ================= fold =================

__global__ __launch_bounds__(256) void fold_kernel(
    const float* __restrict__ Wgcn, const float* __restrict__ bgcn,
    const float* __restrict__ W1, const float* __restrict__ b1,
    float* __restrict__ fold) {
  int t = threadIdx.x;
  if (t < 128) {
    int j = t >> 2, c = t & 3;
    float s = 0.f;
    for (int k = 0; k < 32; ++k) s += Wgcn[c * 32 + k] * W1[(4 + k) * 32 + j];
    fold[j * 4 + c] = s;                    // Wg1T[j][c]
  }
  if (t < 32) {
    float s = 0.f;
    for (int k = 0; k < 32; ++k) s += bgcn[k] * W1[(4 + k) * 32 + t];
    fold[128 + t] = b1[t] + 4.0f * s;       // b1p[j]
  }
}

// ================= binscatter =================

__global__ __launch_bounds__(512) void binscatter_kernel(
    const int* __restrict__ src, const int* __restrict__ dst,
    unsigned* __restrict__ gcur, u64* __restrict__ recs) {
  extern __shared__ char smem[];
  u64* buf = (u64*)smem;                               // [NBIN*LCAP]
  unsigned* cnt = (unsigned*)(smem + NBIN * LCAP * 8); // [NBIN]
  int t = threadIdx.x;
  for (int i = t; i < NBIN; i += 512) cnt[i] = 0;
  __syncthreads();
  const int base = blockIdx.x * SEPB;
  const int limit = min(SEPB, N_EDGES - base);   // >0, multiple of 4
  const int V = limit >> 2;
  const i32x4* src4 = (const i32x4*)(src + base);
  const i32x4* dst4 = (const i32x4*)(dst + base);
  const int nrounds = (V + 1023) / 1024;

  i32x4 cs0 = {0,0,0,0}, cd0 = {0,0,0,0}, cs1 = {0,0,0,0}, cd1 = {0,0,0,0};
  {
    int i0 = t, i1 = t + 512;
    if (i0 < V) { cs0 = __builtin_nontemporal_load(src4 + i0);
                  cd0 = __builtin_nontemporal_load(dst4 + i0); }
    if (i1 < V) { cs1 = __builtin_nontemporal_load(src4 + i1);
                  cd1 = __builtin_nontemporal_load(dst4 + i1); }
  }
  for (int r = 0; r < nrounds; ++r) {
    i32x4 ns0 = {0,0,0,0}, nd0 = {0,0,0,0}, ns1 = {0,0,0,0}, nd1 = {0,0,0,0};
    if (r + 1 < nrounds) {
      int j0 = (r + 1) * 1024 + t, j1 = j0 + 512;
      if (j0 < V) { ns0 = __builtin_nontemporal_load(src4 + j0);
                    nd0 = __builtin_nontemporal_load(dst4 + j0); }
      if (j1 < V) { ns1 = __builtin_nontemporal_load(src4 + j1);
                    nd1 = __builtin_nontemporal_load(dst4 + j1); }
    }
    int idx0 = r * 1024 + t;
#pragma unroll
    for (int half = 0; half < 2; ++half) {
      int idx = idx0 + half * 512;
      if (idx < V) {
        i32x4 vs = half ? cs1 : cs0;
        i32x4 vd = half ? cd1 : cd0;
#pragma unroll
        for (int k = 0; k < 4; ++k) {
          int s = vs[k];
          int d = vd[k];
          unsigned graph = (unsigned)d >> 2;
          unsigned bin   = graph >> 10;
          unsigned glo   = graph & 1023u;
          u64 rec = ((u64)glo << 32) | ((u64)((unsigned)s << 2) | (unsigned)(d & 3));
          unsigned pos = atomicAdd(&cnt[bin], 1u);
          if (pos < LCAP) buf[bin * LCAP + pos] = rec;
          else {  // rare spill
            unsigned p = atomicAdd(&gcur[bin], 1u);
            if (p < BINCAP) recs[(size_t)bin * BINCAP + p] = rec;
          }
        }
      }
    }
    __syncthreads();
    bool fin = (r == nrounds - 1);
    for (int bin = t; bin < NBIN; bin += 512) {
      unsigned c = cnt[bin]; if (c > LCAP) c = LCAP;
      unsigned nn = fin ? c : (c & ~7u);   // 64B bursts
      if (nn) {
        unsigned pos = atomicAdd(&gcur[bin], nn);
        if (pos + nn <= BINCAP) {
          u64* dp = recs + (size_t)bin * BINCAP + pos;
          for (unsigned i2 = 0; i2 < nn; ++i2) dp[i2] = buf[bin * LCAP + i2];
        }
      }
      unsigned rem2 = c - nn;
      for (unsigned i2 = 0; i2 < rem2; ++i2)
        buf[bin * LCAP + i2] = buf[bin * LCAP + nn + i2];
      cnt[bin] = rem2;
    }
    __syncthreads();
    cs0 = ns0; cd0 = nd0; cs1 = ns1; cd1 = nd1;
  }
}

// ================= fused cooperative reduce =================

__global__ __launch_bounds__(512, 8) void fusedreduce_kernel(
    const u64* __restrict__ recs, const unsigned* __restrict__ gcur,
    float4* __restrict__ dsi4, const float4* __restrict__ state4,
    const float* __restrict__ W1, const float* __restrict__ fold,
    const float* __restrict__ W2, const float* __restrict__ b2,
    float* __restrict__ out) {
  extern __shared__ float dynsm[];
  unsigned* degL = (unsigned*)dynsm;   // phase1; becomes dinvL in place
  float* dinvL = dynsm;                // [NPBIN]
  float* accL  = dynsm + NPBIN;        // [NPBIN]
  __shared__ float4 w1aT[32], wg1T[32];
  __shared__ float b1p[32], w2s[32];
  int t = threadIdx.x, bin = blockIdx.x;
  if (t < 32) {
    w1aT[t] = make_float4(W1[t], W1[32 + t], W1[64 + t], W1[96 + t]);
    wg1T[t] = ((const float4*)fold)[t];
    b1p[t]  = fold[128 + t];
    w2s[t]  = W2[t];
  }
  for (int i = t; i < NPBIN; i += 512) { degL[i] = 0u; accL[i] = 0.f; }
  __syncthreads();
  unsigned n = gcur[bin]; if (n > BINCAP) n = BINCAP;
  const u64* rp = recs + (size_t)bin * BINCAP;
  // ---- phase 1: degree histogram over this bin's recs ----
  {
    const u64x2* rv = (const u64x2*)rp;
    unsigned nv = n >> 1;
    for (unsigned i = t; i < nv; i += 512) {
      u64x2 p = __builtin_nontemporal_load(rv + i);
      atomicAdd(&degL[((unsigned)(p.x >> 32)) * 4 + ((unsigned)p.x & 3u)], 1u);
      atomicAdd(&degL[((unsigned)(p.y >> 32)) * 4 + ((unsigned)p.y & 3u)], 1u);
    }
    if ((n & 1u) && t == 0) {
      u64 v = rp[n - 1];
      atomicAdd(&degL[((unsigned)(v >> 32)) * 4 + ((unsigned)v & 3u)], 1u);
    }
  }
  __syncthreads();
  int nb = bin * NPBIN;
  for (int i = t; i < NPBIN; i += 512) {
    int node = nb + i;
    float dv = rsqrtf((float)(degL[i] + 1u));  // +1 self loop
    dinvL[i] = dv;                              // in-place over degL
    if (node < N_NODES) {
      float4 s = state4[node];
      dsi4[node] = make_float4(dv * s.x, dv * s.y, dv * s.z, dv * s.w);
    }
  }
  __threadfence();
  cg::this_grid().sync();
  // ---- phase 2: gather + accumulate (round-7 proven body) ----
  unsigned q = n >> 2;
  for (unsigned i = t; i < q; i += 512) {
    u64 r0 = __builtin_nontemporal_load(rp + i);
    u64 r1 = __builtin_nontemporal_load(rp + i + q);
    u64 r2 = __builtin_nontemporal_load(rp + i + 2 * q);
    u64 r3 = __builtin_nontemporal_load(rp + i + 3 * q);
    unsigned lo0 = (unsigned)r0, g0 = (unsigned)(r0 >> 32), s0 = lo0 >> 2;
    unsigned lo1 = (unsigned)r1, g1 = (unsigned)(r1 >> 32), s1 = lo1 >> 2;
    unsigned lo2 = (unsigned)r2, g2 = (unsigned)(r2 >> 32), s2 = lo2 >> 2;
    unsigned lo3 = (unsigned)r3, g3 = (unsigned)(r3 >> 32), s3 = lo3 >> 2;
    float w0 = dinvL[g0 * 4 + (lo0 & 3u)];
    float w1 = dinvL[g1 * 4 + (lo1 & 3u)];
    float w2 = dinvL[g2 * 4 + (lo2 & 3u)];
    float w3 = dinvL[g3 * 4 + (lo3 & 3u)];
    float4 m0 = dsi4[s0], m1 = dsi4[s1], m2 = dsi4[s2], m3 = dsi4[s3];
    float* a;
    a = accL + g0 * 4;
    atomicAdd(a + 0, w0 * m0.x); atomicAdd(a + 1, w0 * m0.y);
    atomicAdd(a + 2, w0 * m0.z); atomicAdd(a + 3, w0 * m0.w);
    a = accL + g1 * 4;
    atomicAdd(a + 0, w1 * m1.x); atomicAdd(a + 1, w1 * m1.y);
    atomicAdd(a + 2, w1 * m1.z); atomicAdd(a + 3, w1 * m1.w);
    a = accL + g2 * 4;
    atomicAdd(a + 0, w2 * m2.x); atomicAdd(a + 1, w2 * m2.y);
    atomicAdd(a + 2, w2 * m2.z); atomicAdd(a + 3, w2 * m2.w);
    a = accL + g3 * 4;
    atomicAdd(a + 0, w3 * m3.x); atomicAdd(a + 1, w3 * m3.y);
    atomicAdd(a + 2, w3 * m3.z); atomicAdd(a + 3, w3 * m3.w);
  }
  {
    unsigned done = q << 2;
    unsigned rem = n - done;
    if ((unsigned)t < rem) {
      u64 v = rp[done + t];
      unsigned lo = (unsigned)v, g = (unsigned)(v >> 32), s = lo >> 2;
      float w = dinvL[g * 4 + (lo & 3u)];
      float4 mm = dsi4[s];
      float* a = accL + g * 4;
      atomicAdd(a + 0, w * mm.x); atomicAdd(a + 1, w * mm.y);
      atomicAdd(a + 2, w * mm.z); atomicAdd(a + 3, w * mm.w);
    }
  }
  __syncthreads();
  // ---- epilogue: self-loops + fused MLP ----
  for (int gi = t; gi < GPBIN; gi += 512) {
    int g = bin * GPBIN + gi;
    if (g >= N_GRAPHS) break;
    float4 s0 = state4[4 * g + 0], s1 = state4[4 * g + 1];
    float4 s2 = state4[4 * g + 2], s3 = state4[4 * g + 3];
    float d0 = dinvL[gi * 4 + 0], d1 = dinvL[gi * 4 + 1];
    float d2 = dinvL[gi * 4 + 2], d3 = dinvL[gi * 4 + 3];
    float q0 = d0 * d0, q1 = d1 * d1, q2 = d2 * d2, q3 = d3 * d3;
    float ax = accL[gi * 4 + 0] + q0 * s0.x + q1 * s1.x + q2 * s2.x + q3 * s3.x;
    float ay = accL[gi * 4 + 1] + q0 * s0.y + q1 * s1.y + q2 * s2.y + q3 * s3.y;
    float az = accL[gi * 4 + 2] + q0 * s0.z + q1 * s1.z + q2 * s2.z + q3 * s3.z;
    float aw = accL[gi * 4 + 3] + q0 * s0.w + q1 * s1.w + q2 * s2.w + q3 * s3.w;
    float vx = s0.x + s1.x + s2.x + s3.x;
    float vy = s0.y + s1.y + s2.y + s3.y;
    float vz = s0.z + s1.z + s2.z + s3.z;
    float vw = s0.w + s1.w + s2.w + s3.w;
    float accum = b2[0];
#pragma unroll 4
    for (int j = 0; j < 32; ++j) {
      float4 wa = w1aT[j], wg = wg1T[j];
      float h = b1p[j]
              + vx * wa.x + vy * wa.y + vz * wa.z + vw * wa.w
              + ax * wg.x + ay * wg.y + az * wg.z + aw * wg.w;
      accum += fmaxf(h, 0.f) * w2s[j];
    }
    out[g] = accum;
  }
}

// ================= split fallback (bindeg + binreduce) =================

__global__ __launch_bounds__(512) void bindeg_kernel(
    const u64* __restrict__ recs, const unsigned* __restrict__ gcur,
    const float4* __restrict__ state4,
    float* __restrict__ dinv, float4* __restrict__ dsi4) {
  __shared__ unsigned degL[NPBIN];
  int t = threadIdx.x, bin = blockIdx.x;
  for (int i = t; i < NPBIN; i += 512) degL[i] = 0;
  __syncthreads();
  unsigned n = gcur[bin]; if (n > BINCAP) n = BINCAP;
  const u64* rp = recs + (size_t)bin * BINCAP;
  const u64x2* rv = (const u64x2*)rp;
  unsigned nv = n >> 1;
  for (unsigned i = t; i < nv; i += 512) {
    u64x2 p = __builtin_nontemporal_load(rv + i);
    atomicAdd(&degL[((unsigned)(p.x >> 32)) * 4 + ((unsigned)p.x & 3u)], 1u);
    atomicAdd(&degL[((unsigned)(p.y >> 32)) * 4 + ((unsigned)p.y & 3u)], 1u);
  }
  if ((n & 1u) && t == 0) {
    u64 v = rp[n - 1];
    atomicAdd(&degL[((unsigned)(v >> 32)) * 4 + ((unsigned)v & 3u)], 1u);
  }
  __syncthreads();
  int nb = bin * NPBIN;
  for (int i = t; i < NPBIN; i += 512) {
    int node = nb + i;
    if (node < N_NODES) {
      float dv = rsqrtf((float)(degL[i] + 1u));
      dinv[node] = dv;
      float4 s = state4[node];
      dsi4[node] = make_float4(dv * s.x, dv * s.y, dv * s.z, dv * s.w);
    }
  }
}

__global__ __launch_bounds__(512, 8) void binreduce_kernel(
    const u64* __restrict__ recs, const unsigned* __restrict__ gcur,
    const float* __restrict__ dinv, const float4* __restrict__ dsi4,
    const float4* __restrict__ state4,
    const float* __restrict__ W1, const float* __restrict__ fold,
    const float* __restrict__ W2, const float* __restrict__ b2,
    float* __restrict__ out) {
  extern __shared__ float dynsm[];
  float* dinvL = dynsm;
  float* accL  = dynsm + NPBIN;
  __shared__ float4 w1aT[32], wg1T[32];
  __shared__ float b1p[32], w2s[32];
  int t = threadIdx.x, bin = blockIdx.x;
  if (t < 32) {
    w1aT[t] = make_float4(W1[t], W1[32 + t], W1[64 + t], W1[96 + t]);
    wg1T[t] = ((const float4*)fold)[t];
    b1p[t]  = fold[128 + t];
    w2s[t]  = W2[t];
  }
  int nb = bin * NPBIN;
  for (int i = t; i < NPBIN; i += 512) {
    int node = nb + i;
    dinvL[i] = (node < N_NODES) ? dinv[node] : 0.f;
    accL[i]  = 0.f;
  }
  __syncthreads();
  unsigned n = gcur[bin]; if (n > BINCAP) n = BINCAP;
  const u64* rp = recs + (size_t)bin * BINCAP;
  unsigned q = n >> 2;
  for (unsigned i = t; i < q; i += 512) {
    u64 r0 = __builtin_nontemporal_load(rp + i);
    u64 r1 = __builtin_nontemporal_load(rp + i + q);
    u64 r2 = __builtin_nontemporal_load(rp + i + 2 * q);
    u64 r3 = __builtin_nontemporal_load(rp + i + 3 * q);
    unsigned lo0 = (unsigned)r0, g0 = (unsigned)(r0 >> 32), s0 = lo0 >> 2;
    unsigned lo1 = (unsigned)r1, g1 = (unsigned)(r1 >> 32), s1 = lo1 >> 2;
    unsigned lo2 = (unsigned)r2, g2 = (unsigned)(r2 >> 32), s2 = lo2 >> 2;
    unsigned lo3 = (unsigned)r3, g3 = (unsigned)(r3 >> 32), s3 = lo3 >> 2;
    float w0 = dinvL[g0 * 4 + (lo0 & 3u)];
    float w1 = dinvL[g1 * 4 + (lo1 & 3u)];
    float w2 = dinvL[g2 * 4 + (lo2 & 3u)];
    float w3 = dinvL[g3 * 4 + (lo3 & 3u)];
    float4 m0 = dsi4[s0], m1 = dsi4[s1], m2 = dsi4[s2], m3 = dsi4[s3];
    float* a;
    a = accL + g0 * 4;
    atomicAdd(a + 0, w0 * m0.x); atomicAdd(a + 1, w0 * m0.y);
    atomicAdd(a + 2, w0 * m0.z); atomicAdd(a + 3, w0 * m0.w);
    a = accL + g1 * 4;
    atomicAdd(a + 0, w1 * m1.x); atomicAdd(a + 1, w1 * m1.y);
    atomicAdd(a + 2, w1 * m1.z); atomicAdd(a + 3, w1 * m1.w);
    a = accL + g2 * 4;
    atomicAdd(a + 0, w2 * m2.x); atomicAdd(a + 1, w2 * m2.y);
    atomicAdd(a + 2, w2 * m2.z); atomicAdd(a + 3, w2 * m2.w);
    a = accL + g3 * 4;
    atomicAdd(a + 0, w3 * m3.x); atomicAdd(a + 1, w3 * m3.y);
    atomicAdd(a + 2, w3 * m3.z); atomicAdd(a + 3, w3 * m3.w);
  }
  unsigned done = q << 2;
  unsigned rem = n - done;
  if ((unsigned)t < rem) {
    u64 v = rp[done + t];
    unsigned lo = (unsigned)v, g = (unsigned)(v >> 32), s = lo >> 2;
    float w = dinvL[g * 4 + (lo & 3u)];
    float4 mm = dsi4[s];
    float* a = accL + g * 4;
    atomicAdd(a + 0, w * mm.x); atomicAdd(a + 1, w * mm.y);
    atomicAdd(a + 2, w * mm.z); atomicAdd(a + 3, w * mm.w);
  }
  __syncthreads();
  for (int gi = t; gi < GPBIN; gi += 512) {
    int g = bin * GPBIN + gi;
    if (g >= N_GRAPHS) break;
    float4 s0 = state4[4 * g + 0], s1 = state4[4 * g + 1];
    float4 s2 = state4[4 * g + 2], s3 = state4[4 * g + 3];
    float d0 = dinvL[gi * 4 + 0], d1 = dinvL[gi * 4 + 1];
    float d2 = dinvL[gi * 4 + 2], d3 = dinvL[gi * 4 + 3];
    float q0 = d0 * d0, q1 = d1 * d1, q2 = d2 * d2, q3 = d3 * d3;
    float ax = accL[gi * 4 + 0] + q0 * s0.x + q1 * s1.x + q2 * s2.x + q3 * s3.x;
    float ay = accL[gi * 4 + 1] + q0 * s0.y + q1 * s1.y + q2 * s2.y + q3 * s3.y;
    float az = accL[gi * 4 + 2] + q0 * s0.z + q1 * s1.z + q2 * s2.z + q3 * s3.z;
    float aw = accL[gi * 4 + 3] + q0 * s0.w + q1 * s1.w + q2 * s2.w + q3 * s3.w;
    float vx = s0.x + s1.x + s2.x + s3.x;
    float vy = s0.y + s1.y + s2.y + s3.y;
    float vz = s0.z + s1.z + s2.z + s3.z;
    float vw = s0.w + s1.w + s2.w + s3.w;
    float accum = b2[0];
#pragma unroll 4
    for (int j = 0; j < 32; ++j) {
      float4 wa = w1aT[j], wg = wg1T[j];
      float h = b1p[j]
              + vx * wa.x + vy * wa.y + vz * wa.z + vw * wa.w
              + ax * wg.x + ay * wg.y + az * wg.z + aw * wg.w;
      accum += fmaxf(h, 0.f) * w2s[j];
    }
    out[g] = accum;
  }
}

// ================= round-3 emergency fallback =================

__global__ __launch_bounds__(256) void deg_kernel(
    const i32x4* __restrict__ dst4, unsigned* __restrict__ deg) {
  int stride = gridDim.x * blockDim.x;
  for (int e = blockIdx.x * blockDim.x + threadIdx.x; e < N_EDGES / 4; e += stride) {
    i32x4 d = __builtin_nontemporal_load(dst4 + e);
    atomicAdd(&deg[d.x], 1u); atomicAdd(&deg[d.y], 1u);
    atomicAdd(&deg[d.z], 1u); atomicAdd(&deg[d.w], 1u);
  }
}

__global__ __launch_bounds__(256) void dinv_kernel(unsigned* __restrict__ degdinv) {
  int i = blockIdx.x * blockDim.x + threadIdx.x;
  if (i < N_NODES) {
    float dv = rsqrtf((float)(degdinv[i] + 1u));
    reinterpret_cast<float*>(degdinv)[i] = dv;
  }
}

__global__ __launch_bounds__(256) void scatter_kernel(
    const i32x4* __restrict__ src4, const i32x4* __restrict__ dst4,
    const float* __restrict__ dinv, const float4* __restrict__ state4,
    float* __restrict__ acc) {
  int stride = gridDim.x * blockDim.x;
  for (int e = blockIdx.x * blockDim.x + threadIdx.x; e < N_EDGES / 4; e += stride) {
    i32x4 s4 = __builtin_nontemporal_load(src4 + e);
    i32x4 d4 = __builtin_nontemporal_load(dst4 + e);
#pragma unroll
    for (int u = 0; u < 4; ++u) {
      int s = (u == 0) ? s4.x : (u == 1) ? s4.y : (u == 2) ? s4.z : s4.w;
      int d = (u == 0) ? d4.x : (u == 1) ? d4.y : (u == 2) ? d4.z : d4.w;
      float w = dinv[s] * dinv[d];
      float4 st = state4[s];
      float* base = acc + (size_t)(d >> 2) * 4;
      atomicAdd(base + 0, w * st.x); atomicAdd(base + 1, w * st.y);
      atomicAdd(base + 2, w * st.z); atomicAdd(base + 3, w * st.w);
    }
  }
}

__global__ __launch_bounds__(256) void final_kernel(
    const float4* __restrict__ state4, const float4* __restrict__ dinv4,
    const float4* __restrict__ acc4, const float* __restrict__ W1,
    const float* __restrict__ fold, const float* __restrict__ W2,
    const float* __restrict__ b2, float* __restrict__ out) {
  __shared__ float4 w1aT[32], wg1T[32];
  __shared__ float b1p[32], w2s[32];
  int t = threadIdx.x;
  if (t < 32) {
    w1aT[t] = make_float4(W1[t], W1[32 + t], W1[64 + t], W1[96 + t]);
    wg1T[t] = ((const float4*)fold)[t];
    b1p[t]  = fold[128 + t];
    w2s[t]  = W2[t];
  }
  __syncthreads();
  int b = blockIdx.x * blockDim.x + t;
  if (b >= N_GRAPHS) return;
  float4 s0 = state4[4 * b + 0], s1 = state4[4 * b + 1];
  float4 s2 = state4[4 * b + 2], s3 = state4[4 * b + 3];
  float4 dv = dinv4[b];
  float4 a  = acc4[b];
  float q0 = dv.x * dv.x, q1 = dv.y * dv.y, q2 = dv.z * dv.z, q3 = dv.w * dv.w;
  a.x += q0 * s0.x + q1 * s1.x + q2 * s2.x + q3 * s3.x;
  a.y += q0 * s0.y + q1 * s1.y + q2 * s2.y + q3 * s3.y;
  a.z += q0 * s0.z + q1 * s1.z + q2 * s2.z + q3 * s3.z;
  a.w += q0 * s0.w + q1 * s1.w + q2 * s2.w + q3 * s3.w;
  float4 vs;
  vs.x = s0.x + s1.x + s2.x + s3.x;
  vs.y = s0.y + s1.y + s2.y + s3.y;
  vs.z = s0.z + s1.z + s2.z + s3.z;
  vs.w = s0.w + s1.w + s2.w + s3.w;
  float accum = b2[0];
#pragma unroll
  for (int j = 0; j < 32; ++j) {
    float4 wa = w1aT[j], wg = wg1T[j];
    float h = b1p[j]
            + vs.x * wa.x + vs.y * wa.y + vs.z * wa.z + vs.w * wa.w
            + a.x * wg.x + a.y * wg.y + a.z * wg.z + a.w * wg.w;
    accum += fmaxf(h, 0.f) * w2s[j];
  }
  out[b] = accum;
}

// ================= launch =================

extern "C" void kernel_launch(void* const* d_in, const int* in_sizes, int n_in,
                              void* d_out, int out_size, void* d_ws, size_t ws_size,
                              hipStream_t stream) {
  const float* state = (const float*)d_in[0];
  const int*   ei    = (const int*)d_in[1];   // int32: [2][N_EDGES]
  const float* Wgcn  = (const float*)d_in[2];
  const float* bgcn  = (const float*)d_in[3];
  const float* W1    = (const float*)d_in[4];
  const float* b1    = (const float*)d_in[5];
  const float* W2    = (const float*)d_in[6];
  const float* b2    = (const float*)d_in[7];
  float* out = (float*)d_out;

  char* ws = (char*)d_ws;
  const size_t MB = 1024u * 1024u;

  const size_t recs_bytes = (size_t)NBIN * BINCAP * 8;            // 112,050,176
  const size_t dinv_off   = recs_bytes;                            // 16 MB (split path)
  const size_t dsi_off    = dinv_off + (size_t)N_NODES * 4;        // 16B-aligned
  const size_t gcur_off   = (dsi_off + (size_t)N_NODES * 16 + 255) & ~(size_t)255;
  const size_t need_bin   = gcur_off + 8192 + 1024;                // ~192 MB

  const size_t scat_smem = (size_t)NBIN * LCAP * 8 + NBIN * 4;     // 128,964 B
  const size_t red_smem  = 2 * NPBIN * 4;                          // 32 KiB

  if (ws_size >= need_bin) {
    const u64*      recs = (const u64*)ws;
    u64*            recsw = (u64*)ws;
    float*          dinv = (float*)(ws + dinv_off);
    float4*         dsi4 = (float4*)(ws + dsi_off);
    unsigned*       gcur = (unsigned*)(ws + gcur_off);
    float*          fold = (float*)(ws + gcur_off + 8192);
    const float4*   state4 = (const float4*)state;

    (void)hipMemsetAsync(gcur, 0, 8192, stream);
    fold_kernel<<<1, 128, 0, stream>>>(Wgcn, bgcn, W1, b1, fold);
    binscatter_kernel<<<SBLOCKS, 512, scat_smem, stream>>>(
        ei, ei + N_EDGES, gcur, recsw);

    // try cooperative fused path
    bool coop_ok = false;
    {
      int dev = 0;
      (void)hipGetDevice(&dev);
      int coop_attr = 0;
      (void)hipDeviceGetAttribute(&coop_attr, hipDeviceAttributeCooperativeLaunch, dev);
      int numCU = 0;
      (void)hipDeviceGetAttribute(&numCU, hipDeviceAttributeMultiprocessorCount, dev);
      int maxblk = 0;
      hipError_t oe = hipOccupancyMaxActiveBlocksPerMultiprocessor(
          &maxblk, fusedreduce_kernel, 512, red_smem);
      if (coop_attr && oe == hipSuccess && (long)maxblk * numCU >= NBIN) {
        const float* W1p = W1; const float* foldp = fold;
        const float* W2p = W2; const float* b2p = b2;
        void* args[] = {(void*)&recs, (void*)&gcur, (void*)&dsi4, (void*)&state4,
                        (void*)&W1p, (void*)&foldp, (void*)&W2p, (void*)&b2p,
                        (void*)&out};
        hipError_t le = hipLaunchCooperativeKernel(
            fusedreduce_kernel, dim3(NBIN), dim3(512), args,
            (unsigned)red_smem, stream);
        coop_ok = (le == hipSuccess);
      }
    }
    if (!coop_ok) {
      bindeg_kernel<<<NBIN, 512, 0, stream>>>(recs, gcur, state4, dinv, dsi4);
      binreduce_kernel<<<NBIN, 512, red_smem, stream>>>(
          recs, gcur, dinv, dsi4, state4, W1, fold, W2, b2, out);
    }
    return;
  }

  // emergency fallback (33 MB): round-3 atomic-scatter path
  {
    unsigned* deg  = (unsigned*)ws;
    float*    acc  = (float*)(ws + 16 * MB);
    float*    fold = (float*)(ws + 32 * MB);
    (void)hipMemsetAsync(d_ws, 0, 32 * MB + 1024, stream);
    fold_kernel<<<1, 128, 0, stream>>>(Wgcn, bgcn, W1, b1, fold);
    deg_kernel<<<4096, 256, 0, stream>>>((const i32x4*)(ei + N_EDGES), deg);
    dinv_kernel<<<(N_NODES + 255) / 256, 256, 0, stream>>>(deg);
    scatter_kernel<<<8192, 256, 0, stream>>>(
        (const i32x4*)ei, (const i32x4*)(ei + N_EDGES),
        (const float*)deg, (const float4*)state, acc);
    final_kernel<<<(N_GRAPHS + 255) / 256, 256, 0, stream>>>(
        (const float4*)state, (const float4*)deg, (const float4*)acc,
        W1, fold, W2, b2, out);
  }
}